// Round 17
// baseline (1895.965 us; speedup 1.0000x reference)
//
#include <hip/hip_runtime.h>
#include <math.h>

#define BSZ 1024
#define SLEN 32
#define TLEN 32
#define EDIM 128
#define HLD 266
#define HFLD 260

typedef unsigned short u16;
typedef __attribute__((ext_vector_type(8))) short bf16x8;
typedef __attribute__((ext_vector_type(4))) float f32x4;

__device__ __forceinline__ float sgm(float x) { return 1.0f / (1.0f + __expf(-x)); }
__device__ __forceinline__ float tanh_fast(float x) {
  float e = __expf(-2.0f * fabsf(x));
  float t = (1.0f - e) / (1.0f + e);
  return copysignf(t, x);
}
__device__ __forceinline__ u16 f2b(float f) {
  union { float f; unsigned u; } v; v.f = f;
  unsigned r = v.u + 0x7fffu + ((v.u >> 16) & 1u);
  return (u16)(r >> 16);
}
__device__ __forceinline__ float b2f(u16 h) {
  union { unsigned u; float f; } v; v.u = ((unsigned)h) << 16; return v.f;
}
__device__ __forceinline__ void unpk(unsigned p, float& x, float& y) {
  union { unsigned u; float f; } a, b;
  a.u = p << 16; b.u = p & 0xffff0000u;
  x = a.f; y = b.f;
}

typedef __attribute__((address_space(1))) const void gv_t;
typedef __attribute__((address_space(3))) void lv_t;
__device__ __forceinline__ void gload16(const void* g, void* l) {
  __builtin_amdgcn_global_load_lds((gv_t*)g, (lv_t*)l, 16, 0, 0);
}

// ---------------- gi tables -------------------------------------------------------
__global__ __launch_bounds__(256) void k_gi_table(const float* __restrict__ emb,
                                                  const float* __restrict__ Wih, int ldw,
                                                  const float* __restrict__ bih,
                                                  float* __restrict__ tab) {
  int v = blockIdx.x;
  int g = blockIdx.y * 256 + threadIdx.x;
  __shared__ float e[EDIM];
  if (threadIdx.x < EDIM) e[threadIdx.x] = emb[v * EDIM + threadIdx.x];
  __syncthreads();
  const float4* w4 = (const float4*)(Wih + (size_t)g * ldw);
  float acc = 0.f;
#pragma unroll
  for (int j = 0; j < EDIM / 4; ++j) {
    float4 w = w4[j];
    acc += w.x * e[4 * j] + w.y * e[4 * j + 1] + w.z * e[4 * j + 2] + w.w * e[4 * j + 3];
  }
  tab[(size_t)v * 768 + g] = acc + bih[g];
}

// ---------------- gi pre-gather ---------------------------------------------------
__global__ __launch_bounds__(256) void k_gather(const float* __restrict__ tabd,
                                                const int* __restrict__ trg,
                                                float* __restrict__ gi) {
  int t = blockIdx.x, b = blockIdx.y;
  int tok = trg[(size_t)b * TLEN + t];
  const float* src = tabd + (size_t)tok * 768;
  float* dst = gi + ((size_t)t * BSZ + b) * 768;
  for (int g = threadIdx.x; g < 768; g += 256) dst[g] = src[g];
}

// ---------------- fused weight pack (6 segments) ---------------------------------
struct PackArgs {
  u16* dst[6]; const float* src[6]; int ld[6]; int off[6]; int n[6]; int rows[6];
};
__global__ __launch_bounds__(256) void k_pack_all(PackArgs P) {
  int seg = blockIdx.y;
  int r = blockIdx.x;
  if (r >= P.rows[seg]) return;
  u16* dst = P.dst[seg];
  const float* src = P.src[seg];
  int ld = P.ld[seg], off = P.off[seg], n = P.n[seg];
  for (int c = threadIdx.x; c < n; c += 256)
    dst[(size_t)r * n + c] = f2b(src[(size_t)r * ld + off + c]);
}

// gates B matrix (1024 x 768)
__global__ __launch_bounds__(256) void k_pack_gates(u16* __restrict__ Wg,
                                                    const float* __restrict__ dWih,
                                                    const float* __restrict__ dWhh) {
  int r = blockIdx.x;
  for (int c = threadIdx.x; c < 768; c += 256) {
    float v;
    if (r < 512)      v = (c < 512) ? dWih[(size_t)r * 640 + 128 + c] : dWhh[(size_t)r * 256 + (c - 512)];
    else if (r < 768) v = (c < 512) ? dWih[(size_t)r * 640 + 128 + c] : 0.f;
    else              v = (c < 512) ? 0.f : dWhh[(size_t)(r - 256) * 256 + (c - 512)];
    Wg[(size_t)r * 768 + c] = f2b(v);
  }
}

// ---------------- bf16 MFMA GEMM 128x128: out = A.B^T + bias ---------------------
template <bool B16OUT>
__global__ __launch_bounds__(256) void k_bgemm2(const u16* __restrict__ A, int lda,
                                                const u16* __restrict__ B, int ldb,
                                                const float* __restrict__ bias,
                                                void* __restrict__ outv, int ldo, int K) {
  __shared__ u16 sA[128 * 64];
  __shared__ u16 sB[128 * 64];
  int m0 = blockIdx.x * 128, n0 = blockIdx.y * 128;
  int tid = threadIdx.x, w = tid >> 6, l = tid & 63;
  int wr = w >> 1, wc = w & 1;
  f32x4 acc[4][4] = {};
  for (int k0 = 0; k0 < K; k0 += 64) {
    __syncthreads();
#pragma unroll
    for (int i = 0; i < 4; ++i) {
      int chunk = i * 4 + w;
      int d = chunk * 1024 + l * 16;
      int lg = d ^ (((d >> 7) & 7) << 4);
      int row = lg >> 7, kb = lg & 127;
      gload16((const char*)(A + (size_t)(m0 + row) * lda + k0) + kb, (char*)sA + chunk * 1024);
    }
#pragma unroll
    for (int i = 0; i < 4; ++i) {
      int chunk = i * 4 + w;
      int d = chunk * 1024 + l * 16;
      int lg = d ^ (((d >> 7) & 7) << 4);
      int row = lg >> 7, kb = lg & 127;
      gload16((const char*)(B + (size_t)(n0 + row) * ldb + k0) + kb, (char*)sB + chunk * 1024);
    }
    __syncthreads();
#pragma unroll
    for (int kk = 0; kk < 2; ++kk) {
      bf16x8 av[4], bv[4];
#pragma unroll
      for (int fm = 0; fm < 4; ++fm) {
        int row = wr * 64 + fm * 16 + (l & 15);
        int addr = (row * 128 + kk * 64 + (l >> 4) * 16) ^ ((row & 7) << 4);
        av[fm] = *(const bf16x8*)((const char*)sA + addr);
      }
#pragma unroll
      for (int fn = 0; fn < 4; ++fn) {
        int row = wc * 64 + fn * 16 + (l & 15);
        int addr = (row * 128 + kk * 64 + (l >> 4) * 16) ^ ((row & 7) << 4);
        bv[fn] = *(const bf16x8*)((const char*)sB + addr);
      }
#pragma unroll
      for (int fm = 0; fm < 4; ++fm)
#pragma unroll
        for (int fn = 0; fn < 4; ++fn)
          acc[fm][fn] = __builtin_amdgcn_mfma_f32_16x16x32_bf16(av[fm], bv[fn], acc[fm][fn], 0, 0, 0);
    }
  }
#pragma unroll
  for (int fn = 0; fn < 4; ++fn) {
    int c = n0 + wc * 64 + fn * 16 + (l & 15);
    float bb = bias ? bias[c] : 0.f;
#pragma unroll
    for (int fm = 0; fm < 4; ++fm) {
      int r = m0 + wr * 64 + fm * 16 + (l >> 4) * 4;
#pragma unroll
      for (int j = 0; j < 4; ++j) {
        float val = acc[fm][fn][j] + bb;
        if (B16OUT) ((u16*)outv)[(size_t)(r + j) * ldo + c] = f2b(val);
        else        ((float*)outv)[(size_t)(r + j) * ldo + c] = val;
      }
    }
  }
}

// ---------------- batched logits GEMM 128x128: bcat @ Wfc^T -> dout scatter ------
__global__ __launch_bounds__(256) void k_bgemm_logits(const u16* __restrict__ A,
                                                      const u16* __restrict__ B,
                                                      const float* __restrict__ bias,
                                                      float* __restrict__ dout) {
  __shared__ u16 sA[128 * 64];
  __shared__ u16 sB[128 * 64];
  int m0 = blockIdx.x * 128, n0 = blockIdx.y * 128;
  int tid = threadIdx.x, w = tid >> 6, l = tid & 63;
  int wr = w >> 1, wc = w & 1;
  f32x4 acc[4][4] = {};
  for (int k0 = 0; k0 < 768; k0 += 64) {
    __syncthreads();
#pragma unroll
    for (int i = 0; i < 4; ++i) {
      int chunk = i * 4 + w;
      int d = chunk * 1024 + l * 16;
      int lg = d ^ (((d >> 7) & 7) << 4);
      int row = lg >> 7, kb = lg & 127;
      gload16((const char*)(A + (size_t)(m0 + row) * 768 + k0) + kb, (char*)sA + chunk * 1024);
    }
#pragma unroll
    for (int i = 0; i < 4; ++i) {
      int chunk = i * 4 + w;
      int d = chunk * 1024 + l * 16;
      int lg = d ^ (((d >> 7) & 7) << 4);
      int row = lg >> 7, kb = lg & 127;
      gload16((const char*)(B + (size_t)(n0 + row) * 768 + k0) + kb, (char*)sB + chunk * 1024);
    }
    __syncthreads();
#pragma unroll
    for (int kk = 0; kk < 2; ++kk) {
      bf16x8 av[4], bv[4];
#pragma unroll
      for (int fm = 0; fm < 4; ++fm) {
        int row = wr * 64 + fm * 16 + (l & 15);
        int addr = (row * 128 + kk * 64 + (l >> 4) * 16) ^ ((row & 7) << 4);
        av[fm] = *(const bf16x8*)((const char*)sA + addr);
      }
#pragma unroll
      for (int fn = 0; fn < 4; ++fn) {
        int row = wc * 64 + fn * 16 + (l & 15);
        int addr = (row * 128 + kk * 64 + (l >> 4) * 16) ^ ((row & 7) << 4);
        bv[fn] = *(const bf16x8*)((const char*)sB + addr);
      }
#pragma unroll
      for (int fm = 0; fm < 4; ++fm)
#pragma unroll
        for (int fn = 0; fn < 4; ++fn)
          acc[fm][fn] = __builtin_amdgcn_mfma_f32_16x16x32_bf16(av[fm], bv[fn], acc[fm][fn], 0, 0, 0);
    }
  }
#pragma unroll
  for (int fn = 0; fn < 4; ++fn) {
    int c = n0 + wc * 64 + fn * 16 + (l & 15);
    float bb = bias[c];
#pragma unroll
    for (int fm = 0; fm < 4; ++fm) {
#pragma unroll
      for (int j = 0; j < 4; ++j) {
        int gr = m0 + wr * 64 + fm * 16 + (l >> 4) * 4 + j;
        int tt = gr >> 10, b = gr & 1023;
        dout[(size_t)b * (TLEN * 256) + (size_t)(tt + 1) * 256 + c] = acc[fm][fn][j] + bb;
      }
    }
  }
}

// ---------------- encoder v3: 256 blocks = 128 rowgrps x 2 dirs, 8 rows ----------
struct EncArgs {
  u16* enc_b; u16* hcatB; const int* src;
  const u16* Whhf; const u16* Whhb;
  const float* bhhf; const float* bhhb;
  const float* tabf; const float* tabb;
};

__global__ __launch_bounds__(1024, 4) void k_enc_p(EncArgs E) {
  __shared__ float hF[8 * HFLD];
  __shared__ u16 hB[16 * HLD];  // rows 8-15 stay zero (A-frag over-read)
  __shared__ int toks[256];
  int dir = blockIdx.x & 1;
  int r0 = (blockIdx.x >> 1) * 8;
  int tid = threadIdx.x, w = tid >> 6, l = tid & 63;
  const u16* Whh = dir ? E.Whhb : E.Whhf;
  const float* tab = dir ? E.tabb : E.tabf;
  const float* bhh = dir ? E.bhhb : E.bhhf;
  bf16x8 wreg[8][3];
#pragma unroll
  for (int kk = 0; kk < 8; ++kk)
#pragma unroll
    for (int g = 0; g < 3; ++g)
      wreg[kk][g] = *(const bf16x8*)(Whh +
          (size_t)(g * 256 + w * 16 + (l & 15)) * 256 + kk * 32 + (l >> 4) * 8);
  for (int i = tid; i < 16 * HLD; i += 1024) hB[i] = 0;
  for (int i = tid; i < 8 * HFLD; i += 1024) hF[i] = 0.f;
  if (tid < 256) toks[tid] = E.src[(size_t)(r0 + (tid >> 5)) * SLEN + (tid & 31)];
  __syncthreads();
  for (int s = 0; s < SLEN; ++s) {
    int s_store = dir ? (SLEN - 1 - s) : s;
    f32x4 ae[3] = {};
    if (s > 0) {
#pragma unroll
      for (int kk = 0; kk < 8; ++kk) {
        bf16x8 av = *(const bf16x8*)(hB + (l & 15) * HLD + kk * 32 + (l >> 4) * 8);
#pragma unroll
        for (int g = 0; g < 3; ++g)
          ae[g] = __builtin_amdgcn_mfma_f32_16x16x32_bf16(av, wreg[kk][g], ae[g], 0, 0, 0);
      }
    }
    __syncthreads();
    int c = w * 16 + (l & 15);
    float bR = bhh[c], bZ = bhh[256 + c], bN = bhh[512 + c];
#pragma unroll
    for (int j = 0; j < 4; ++j) {
      int row = (l >> 4) * 4 + j;
      if (row < 8) {
        const float* tb = tab + (size_t)toks[row * 32 + s_store] * 768 + c;
        float rg = sgm(tb[0] + ae[0][j] + bR);
        float zg = sgm(tb[256] + ae[1][j] + bZ);
        float ng = tanh_fast(tb[512] + rg * (ae[2][j] + bN));
        float hold = hF[row * HFLD + c];
        float hv = (1.f - zg) * ng + zg * hold;
        hF[row * HFLD + c] = hv;
        u16 hb16 = f2b(hv);
        hB[row * HLD + c] = hb16;
        E.enc_b[((size_t)(r0 + row) * SLEN + s_store) * 512 + dir * 256 + c] = hb16;
      }
    }
    __syncthreads();
  }
  for (int i = tid; i < 8 * 256; i += 1024) {
    int row = i >> 8, c = i & 255;
    E.hcatB[(size_t)(r0 + row) * 512 + dir * 256 + c] = hB[row * HLD + c];
  }
}

// ---------------- K1: attn8 with fused GRU-epilogue prologue ---------------------
__global__ __launch_bounds__(256) void k_attn8_ep(u16* __restrict__ cat,
                                                  const u16* __restrict__ enc_pre_b,
                                                  const u16* __restrict__ enc_b,
                                                  const float* __restrict__ v_attn,
                                                  const u16* __restrict__ Wd_b,
                                                  u16* __restrict__ bcat_t,
                                                  const float* __restrict__ gbuf,
                                                  const float* __restrict__ gi_prev,
                                                  const float* __restrict__ dbhh,
                                                  const float* __restrict__ h_cur,
                                                  float* __restrict__ h_nxt,
                                                  u16* __restrict__ bcat_prev,
                                                  int do_ep) {
  __shared__ __align__(16) char smem[10240];
  float* hwS = (float*)smem;           // 8 x 256
  float* vS = (float*)(smem + 8192);   // 256
  float* awS = (float*)(smem + 9216);  // 8 x 32
  int b0 = blockIdx.x * 8;
  int tid = threadIdx.x, w = tid >> 6, l = tid & 63;
  vS[tid] = v_attn[tid];
  if (do_ep) {
    int row = b0 + (tid >> 5);
    int c0 = (tid & 31) * 8;
    const float* g = gbuf + (size_t)row * 1024;
    const float* gi = gi_prev + (size_t)(row) * 768;
#pragma unroll
    for (int q = 0; q < 8; ++q) {
      int c = c0 + q;
      float rg = sgm(gi[c] + g[c] + dbhh[c]);
      float zg = sgm(gi[256 + c] + g[256 + c] + dbhh[256 + c]);
      float ng = tanh_fast(gi[512 + c] + g[512 + c] + rg * (g[768 + c] + dbhh[512 + c]));
      float hold = h_cur[(size_t)row * 256 + c];
      float hv = (1.f - zg) * ng + zg * hold;
      h_nxt[(size_t)row * 256 + c] = hv;
      u16 hb = f2b(hv);
      cat[(size_t)row * 768 + 512 + c] = hb;
      bcat_prev[(size_t)row * 768 + c] = hb;
    }
  }
  __syncthreads();
  f32x4 acc[4] = {};
  for (int k0 = 0; k0 < 256; k0 += 32) {
    bf16x8 av = *(const bf16x8*)(cat + (size_t)(b0 + (l & 15)) * 768 + 512 + k0 + (l >> 4) * 8);
#pragma unroll
    for (int fn = 0; fn < 4; ++fn) {
      bf16x8 bv = *(const bf16x8*)(Wd_b + (size_t)(w * 64 + fn * 16 + (l & 15)) * 256 +
                                   k0 + (l >> 4) * 8);
      acc[fn] = __builtin_amdgcn_mfma_f32_16x16x32_bf16(av, bv, acc[fn], 0, 0, 0);
    }
  }
#pragma unroll
  for (int fn = 0; fn < 4; ++fn) {
    int c = w * 64 + fn * 16 + (l & 15);
#pragma unroll
    for (int j = 0; j < 4; ++j) {
      int r = (l >> 4) * 4 + j;
      if (r < 8) hwS[r * 256 + c] = acc[fn][j];
    }
  }
  __syncthreads();
  int r = tid >> 5, s = tid & 31;
  const u16* ep = enc_pre_b + ((size_t)(b0 + r) * SLEN + s) * 256;
  float sum = 0.f;
  for (int a0 = 0; a0 < 256; a0 += 8) {
    bf16x8 pk = *(const bf16x8*)(ep + a0);
    float4 h0 = *(const float4*)&hwS[r * 256 + a0];
    float4 h1 = *(const float4*)&hwS[r * 256 + a0 + 4];
    float4 v0 = *(const float4*)&vS[a0];
    float4 v1 = *(const float4*)&vS[a0 + 4];
    sum += v0.x * tanh_fast(b2f((u16)pk[0]) + h0.x) + v0.y * tanh_fast(b2f((u16)pk[1]) + h0.y) +
           v0.z * tanh_fast(b2f((u16)pk[2]) + h0.z) + v0.w * tanh_fast(b2f((u16)pk[3]) + h0.w) +
           v1.x * tanh_fast(b2f((u16)pk[4]) + h1.x) + v1.y * tanh_fast(b2f((u16)pk[5]) + h1.y) +
           v1.z * tanh_fast(b2f((u16)pk[6]) + h1.z) + v1.w * tanh_fast(b2f((u16)pk[7]) + h1.w);
  }
  float m = sum;
#pragma unroll
  for (int o = 16; o >= 1; o >>= 1) m = fmaxf(m, __shfl_xor(m, o, 32));
  float e = __expf(sum - m), ss = e;
#pragma unroll
  for (int o = 16; o >= 1; o >>= 1) ss += __shfl_xor(ss, o, 32);
  awS[r * 32 + s] = e / ss;
  __syncthreads();
  int c = tid * 2;
#pragma unroll
  for (int rr = 0; rr < 8; ++rr) {
    float ax = 0.f, ay = 0.f;
    const u16* eb = enc_b + (size_t)(b0 + rr) * (SLEN * 512) + c;
#pragma unroll 8
    for (int si = 0; si < 32; ++si) {
      float a = awS[rr * 32 + si];
      unsigned pk = *(const unsigned*)(eb + si * 512);
      float x, y; unpk(pk, x, y);
      ax += a * x; ay += a * y;
    }
    unsigned o = (unsigned)f2b(ax) | ((unsigned)f2b(ay) << 16);
    *(unsigned*)(cat + (size_t)(b0 + rr) * 768 + c) = o;
    *(unsigned*)(bcat_t + (size_t)(b0 + rr) * 768 + 256 + c) = o;
  }
}

// ---------------- final GRU epilogue (t=30) --------------------------------------
__global__ __launch_bounds__(256) void k_gru_ep(const float* __restrict__ gbuf,
                                                const float* __restrict__ gi_t,
                                                const float* __restrict__ dbhh,
                                                const float* __restrict__ h_cur,
                                                float* __restrict__ h_nxt,
                                                u16* __restrict__ bcat_t) {
  int row = blockIdx.x, c = threadIdx.x;
  const float* g = gbuf + (size_t)row * 1024;
  const float* gi = gi_t + (size_t)row * 768;
  float rg = sgm(gi[c] + g[c] + dbhh[c]);
  float zg = sgm(gi[256 + c] + g[256 + c] + dbhh[256 + c]);
  float ng = tanh_fast(gi[512 + c] + g[512 + c] + rg * (g[768 + c] + dbhh[512 + c]));
  float hold = h_cur[(size_t)row * 256 + c];
  float hv = (1.f - zg) * ng + zg * hold;
  h_nxt[(size_t)row * 256 + c] = hv;
  bcat_t[(size_t)row * 768 + c] = f2b(hv);
}

// ---------------- h fp32 -> bf16 into cat[512:768] -------------------------------
__global__ __launch_bounds__(256) void k_h2b(const float* __restrict__ h,
                                             u16* __restrict__ cat) {
  int row = blockIdx.x, c = threadIdx.x;
  cat[(size_t)row * 768 + 512 + c] = f2b(h[(size_t)row * 256 + c]);
}

// ---------------- zero t=0 slice -------------------------------------------------
__global__ __launch_bounds__(256) void k_zero0(float* __restrict__ outp) {
  outp[(size_t)blockIdx.x * (TLEN * 256) + threadIdx.x] = 0.f;
}

extern "C" void kernel_launch(void* const* d_in, const int* in_sizes, int n_in,
                              void* d_out, int out_size, void* d_ws, size_t ws_size,
                              hipStream_t stream) {
  (void)in_sizes; (void)n_in; (void)out_size; (void)ws_size;
  const int* src = (const int*)d_in[0];
  const int* trg = (const int*)d_in[1];
  const float* enc_emb = (const float*)d_in[2];
  const float* eWih_f = (const float*)d_in[3];
  const float* eWhh_f = (const float*)d_in[4];
  const float* ebih_f = (const float*)d_in[5];
  const float* ebhh_f = (const float*)d_in[6];
  const float* eWih_b = (const float*)d_in[7];
  const float* eWhh_b = (const float*)d_in[8];
  const float* ebih_b = (const float*)d_in[9];
  const float* ebhh_b = (const float*)d_in[10];
  const float* Wproj = (const float*)d_in[11];
  const float* bproj = (const float*)d_in[12];
  const float* dec_emb = (const float*)d_in[13];
  const float* Wattn = (const float*)d_in[14];
  const float* battn = (const float*)d_in[15];
  const float* v_attn = (const float*)d_in[16];
  const float* dWih = (const float*)d_in[17];
  const float* dWhh = (const float*)d_in[18];
  const float* dbih = (const float*)d_in[19];
  const float* dbhh = (const float*)d_in[20];
  const float* Wfc = (const float*)d_in[21];
  const float* bfc = (const float*)d_in[22];
  float* dout = (float*)d_out;

  char* base = (char*)d_ws;
  size_t off = 0;
  auto alloc = [&](size_t bytes) {
    void* p = base + off;
    off += (bytes + 255) & ~(size_t)255;
    return p;
  };
  u16* enc_b     = (u16*)alloc((size_t)BSZ * SLEN * 512 * 2);
  u16* enc_pre_b = (u16*)alloc((size_t)BSZ * SLEN * 256 * 2);
  u16* bcat      = (u16*)alloc((size_t)31 * BSZ * 768 * 2);
  float* gi_t    = (float*)alloc((size_t)31 * BSZ * 768 * 4);
  float* gbuf    = (float*)alloc((size_t)BSZ * 1024 * 4);
  float* tabf    = (float*)alloc((size_t)64 * 768 * 4);
  float* tabb    = (float*)alloc((size_t)64 * 768 * 4);
  float* tabd    = (float*)alloc((size_t)256 * 768 * 4);
  u16* hcatB     = (u16*)alloc((size_t)BSZ * 512 * 2);
  float* h0f     = (float*)alloc((size_t)BSZ * 256 * 4);
  float* h1f     = (float*)alloc((size_t)BSZ * 256 * 4);
  u16* Whhf_b    = (u16*)alloc((size_t)768 * 256 * 2);
  u16* Whhb_b    = (u16*)alloc((size_t)768 * 256 * 2);
  u16* We_b      = (u16*)alloc((size_t)256 * 512 * 2);
  u16* Wd_b      = (u16*)alloc((size_t)256 * 256 * 2);
  u16* Wproj_b   = (u16*)alloc((size_t)256 * 512 * 2);
  u16* Wg        = (u16*)alloc((size_t)1024 * 768 * 2);
  u16* Wfc_b     = (u16*)alloc((size_t)256 * 768 * 2);
  u16* cat0      = (u16*)alloc((size_t)BSZ * 768 * 2);
  u16* cat1      = (u16*)alloc((size_t)BSZ * 768 * 2);
  (void)alloc(65536);  // pad: attn8 A-fragments over-read past last rows

  float* hbuf[2] = {h0f, h1f};

  // tables + weight packs
  k_gi_table<<<dim3(64, 3), 256, 0, stream>>>(enc_emb, eWih_f, EDIM, ebih_f, tabf);
  k_gi_table<<<dim3(64, 3), 256, 0, stream>>>(enc_emb, eWih_b, EDIM, ebih_b, tabb);
  k_gi_table<<<dim3(256, 3), 256, 0, stream>>>(dec_emb, dWih, 640, dbih, tabd);
  k_gather<<<dim3(TLEN - 1, BSZ), 256, 0, stream>>>(tabd, trg, gi_t);
  {
    PackArgs P;
    P.dst[0] = Whhf_b;  P.src[0] = eWhh_f; P.ld[0] = 256; P.off[0] = 0;   P.n[0] = 256; P.rows[0] = 768;
    P.dst[1] = Whhb_b;  P.src[1] = eWhh_b; P.ld[1] = 256; P.off[1] = 0;   P.n[1] = 256; P.rows[1] = 768;
    P.dst[2] = We_b;    P.src[2] = Wattn;  P.ld[2] = 768; P.off[2] = 256; P.n[2] = 512; P.rows[2] = 256;
    P.dst[3] = Wd_b;    P.src[3] = Wattn;  P.ld[3] = 768; P.off[3] = 0;   P.n[3] = 256; P.rows[3] = 256;
    P.dst[4] = Wproj_b; P.src[4] = Wproj;  P.ld[4] = 512; P.off[4] = 0;   P.n[4] = 512; P.rows[4] = 256;
    P.dst[5] = Wfc_b;   P.src[5] = Wfc;    P.ld[5] = 768; P.off[5] = 0;   P.n[5] = 768; P.rows[5] = 256;
    k_pack_all<<<dim3(768, 6), 256, 0, stream>>>(P);
  }
  k_pack_gates<<<dim3(1024), 256, 0, stream>>>(Wg, dWih, dWhh);

  // encoder v3: register-resident weights
  {
    EncArgs ea{enc_b, hcatB, src, Whhf_b, Whhb_b, ebhh_f, ebhh_b, tabf, tabb};
    k_enc_p<<<dim3(256), dim3(1024), 0, stream>>>(ea);
  }

  // hdec = hcat @ Wproj^T + bproj (fp32), then bf16 into cat0[512:768]
  k_bgemm2<false><<<dim3(8, 2), 256, 0, stream>>>(hcatB, 512, Wproj_b, 512, bproj, h0f, 256, 512);
  k_h2b<<<dim3(BSZ), 256, 0, stream>>>(h0f, cat0);

  // enc_pre (bf16) = enc_b @ We^T + battn
  k_bgemm2<true><<<dim3(256, 2), 256, 0, stream>>>(enc_b, 512, We_b, 512, battn,
                                                   enc_pre_b, 256, 512);
  k_zero0<<<dim3(BSZ), 256, 0, stream>>>(dout);

  // decoder: 31 steps x 2 kernels (ep fused into next attn8) + final ep
  for (int t = 0; t < TLEN - 1; ++t) {
    u16* cc = (t & 1) ? cat1 : cat0;
    u16* bt = bcat + (size_t)t * BSZ * 768;
    const float* gip = (t > 0) ? (gi_t + (size_t)(t - 1) * BSZ * 768) : gi_t;
    u16* btp = (t > 0) ? (bcat + (size_t)(t - 1) * BSZ * 768) : bcat;
    k_attn8_ep<<<dim3(128), 256, 0, stream>>>(cc, enc_pre_b, enc_b, v_attn, Wd_b, bt,
                                              gbuf, gip, dbhh, hbuf[(t + 1) & 1],
                                              hbuf[t & 1], btp, (t > 0) ? 1 : 0);
    k_bgemm2<false><<<dim3(8, 8), 256, 0, stream>>>(cc, 768, Wg, 768, nullptr, gbuf, 1024, 768);
  }
  // final epilogue for t=30
  k_gru_ep<<<dim3(BSZ), 256, 0, stream>>>(gbuf, gi_t + (size_t)30 * BSZ * 768, dbhh,
                                          hbuf[0], hbuf[1], bcat + (size_t)30 * BSZ * 768);

  // deferred logits
  k_bgemm_logits<<<dim3(248, 2), 256, 0, stream>>>(bcat, Wfc_b, bfc, dout);
}

// Round 18
// 1749.681 us; speedup vs baseline: 1.0836x; 1.0836x over previous
//
#include <hip/hip_runtime.h>
#include <math.h>

#define BSZ 1024
#define SLEN 32
#define TLEN 32
#define EDIM 128
#define HLD 266
#define HFLD 260

typedef unsigned short u16;
typedef __attribute__((ext_vector_type(8))) short bf16x8;
typedef __attribute__((ext_vector_type(4))) float f32x4;

__device__ __forceinline__ float sgm(float x) { return 1.0f / (1.0f + __expf(-x)); }
__device__ __forceinline__ float tanh_fast(float x) {
  float e = __expf(-2.0f * fabsf(x));
  float t = (1.0f - e) / (1.0f + e);
  return copysignf(t, x);
}
__device__ __forceinline__ u16 f2b(float f) {
  union { float f; unsigned u; } v; v.f = f;
  unsigned r = v.u + 0x7fffu + ((v.u >> 16) & 1u);
  return (u16)(r >> 16);
}
__device__ __forceinline__ float b2f(u16 h) {
  union { unsigned u; float f; } v; v.u = ((unsigned)h) << 16; return v.f;
}
__device__ __forceinline__ void unpk(unsigned p, float& x, float& y) {
  union { unsigned u; float f; } a, b;
  a.u = p << 16; b.u = p & 0xffff0000u;
  x = a.f; y = b.f;
}

typedef __attribute__((address_space(1))) const void gv_t;
typedef __attribute__((address_space(3))) void lv_t;
__device__ __forceinline__ void gload16(const void* g, void* l) {
  __builtin_amdgcn_global_load_lds((gv_t*)g, (lv_t*)l, 16, 0, 0);
}

// ---------------- gi tables -------------------------------------------------------
__global__ __launch_bounds__(256) void k_gi_table(const float* __restrict__ emb,
                                                  const float* __restrict__ Wih, int ldw,
                                                  const float* __restrict__ bih,
                                                  float* __restrict__ tab) {
  int v = blockIdx.x;
  int g = blockIdx.y * 256 + threadIdx.x;
  __shared__ float e[EDIM];
  if (threadIdx.x < EDIM) e[threadIdx.x] = emb[v * EDIM + threadIdx.x];
  __syncthreads();
  const float4* w4 = (const float4*)(Wih + (size_t)g * ldw);
  float acc = 0.f;
#pragma unroll
  for (int j = 0; j < EDIM / 4; ++j) {
    float4 w = w4[j];
    acc += w.x * e[4 * j] + w.y * e[4 * j + 1] + w.z * e[4 * j + 2] + w.w * e[4 * j + 3];
  }
  tab[(size_t)v * 768 + g] = acc + bih[g];
}

// ---------------- gi pre-gather ---------------------------------------------------
__global__ __launch_bounds__(256) void k_gather(const float* __restrict__ tabd,
                                                const int* __restrict__ trg,
                                                float* __restrict__ gi) {
  int t = blockIdx.x, b = blockIdx.y;
  int tok = trg[(size_t)b * TLEN + t];
  const float* src = tabd + (size_t)tok * 768;
  float* dst = gi + ((size_t)t * BSZ + b) * 768;
  for (int g = threadIdx.x; g < 768; g += 256) dst[g] = src[g];
}

// ---------------- fused weight pack (6 segments) ---------------------------------
struct PackArgs {
  u16* dst[6]; const float* src[6]; int ld[6]; int off[6]; int n[6]; int rows[6];
};
__global__ __launch_bounds__(256) void k_pack_all(PackArgs P) {
  int seg = blockIdx.y;
  int r = blockIdx.x;
  if (r >= P.rows[seg]) return;
  u16* dst = P.dst[seg];
  const float* src = P.src[seg];
  int ld = P.ld[seg], off = P.off[seg], n = P.n[seg];
  for (int c = threadIdx.x; c < n; c += 256)
    dst[(size_t)r * n + c] = f2b(src[(size_t)r * ld + off + c]);
}

// gates B matrix (1024 x 768)
__global__ __launch_bounds__(256) void k_pack_gates(u16* __restrict__ Wg,
                                                    const float* __restrict__ dWih,
                                                    const float* __restrict__ dWhh) {
  int r = blockIdx.x;
  for (int c = threadIdx.x; c < 768; c += 256) {
    float v;
    if (r < 512)      v = (c < 512) ? dWih[(size_t)r * 640 + 128 + c] : dWhh[(size_t)r * 256 + (c - 512)];
    else if (r < 768) v = (c < 512) ? dWih[(size_t)r * 640 + 128 + c] : 0.f;
    else              v = (c < 512) ? 0.f : dWhh[(size_t)(r - 256) * 256 + (c - 512)];
    Wg[(size_t)r * 768 + c] = f2b(v);
  }
}

// ---------------- bf16 MFMA GEMM 128x64: out = A.B^T + bias ----------------------
template <bool B16OUT>
__global__ __launch_bounds__(256) void k_bgemm(const u16* __restrict__ A, int lda,
                                               const u16* __restrict__ B, int ldb,
                                               const float* __restrict__ bias,
                                               void* __restrict__ outv, int ldo, int K) {
  __shared__ u16 sA[128 * 64];
  __shared__ u16 sB[64 * 64];
  int m0 = blockIdx.x * 128, n0 = blockIdx.y * 64;
  int tid = threadIdx.x, w = tid >> 6, l = tid & 63;
  int wr = w >> 1, wc = w & 1;
  f32x4 acc[4][2] = {};
  for (int k0 = 0; k0 < K; k0 += 64) {
    __syncthreads();
#pragma unroll
    for (int i = 0; i < 4; ++i) {
      int chunk = i * 4 + w;
      int d = chunk * 1024 + l * 16;
      int lg = d ^ (((d >> 7) & 7) << 4);
      int row = lg >> 7, kb = lg & 127;
      gload16((const char*)(A + (size_t)(m0 + row) * lda + k0) + kb, (char*)sA + chunk * 1024);
    }
#pragma unroll
    for (int i = 0; i < 2; ++i) {
      int chunk = i * 4 + w;
      int d = chunk * 1024 + l * 16;
      int lg = d ^ (((d >> 7) & 7) << 4);
      int row = lg >> 7, kb = lg & 127;
      gload16((const char*)(B + (size_t)(n0 + row) * ldb + k0) + kb, (char*)sB + chunk * 1024);
    }
    __syncthreads();
#pragma unroll
    for (int kk = 0; kk < 2; ++kk) {
      bf16x8 av[4], bv[2];
#pragma unroll
      for (int fm = 0; fm < 4; ++fm) {
        int row = wr * 64 + fm * 16 + (l & 15);
        int addr = (row * 128 + kk * 64 + (l >> 4) * 16) ^ ((row & 7) << 4);
        av[fm] = *(const bf16x8*)((const char*)sA + addr);
      }
#pragma unroll
      for (int fn = 0; fn < 2; ++fn) {
        int row = wc * 32 + fn * 16 + (l & 15);
        int addr = (row * 128 + kk * 64 + (l >> 4) * 16) ^ ((row & 7) << 4);
        bv[fn] = *(const bf16x8*)((const char*)sB + addr);
      }
#pragma unroll
      for (int fm = 0; fm < 4; ++fm)
#pragma unroll
        for (int fn = 0; fn < 2; ++fn)
          acc[fm][fn] = __builtin_amdgcn_mfma_f32_16x16x32_bf16(av[fm], bv[fn], acc[fm][fn], 0, 0, 0);
    }
  }
#pragma unroll
  for (int fn = 0; fn < 2; ++fn) {
    int c = n0 + wc * 32 + fn * 16 + (l & 15);
    float bb = bias ? bias[c] : 0.f;
#pragma unroll
    for (int fm = 0; fm < 4; ++fm) {
      int r = m0 + wr * 64 + fm * 16 + (l >> 4) * 4;
#pragma unroll
      for (int j = 0; j < 4; ++j) {
        float val = acc[fm][fn][j] + bb;
        if (B16OUT) ((u16*)outv)[(size_t)(r + j) * ldo + c] = f2b(val);
        else        ((float*)outv)[(size_t)(r + j) * ldo + c] = val;
      }
    }
  }
}

// ---------------- batched logits GEMM: bcat(31744x768) @ Wfc^T -> dout scatter ----
__global__ __launch_bounds__(256) void k_bgemm_logits(const u16* __restrict__ A,
                                                      const u16* __restrict__ B,
                                                      const float* __restrict__ bias,
                                                      float* __restrict__ dout) {
  __shared__ u16 sA[128 * 64];
  __shared__ u16 sB[64 * 64];
  int m0 = blockIdx.x * 128, n0 = blockIdx.y * 64;
  int tid = threadIdx.x, w = tid >> 6, l = tid & 63;
  int wr = w >> 1, wc = w & 1;
  f32x4 acc[4][2] = {};
  for (int k0 = 0; k0 < 768; k0 += 64) {
    __syncthreads();
#pragma unroll
    for (int i = 0; i < 4; ++i) {
      int chunk = i * 4 + w;
      int d = chunk * 1024 + l * 16;
      int lg = d ^ (((d >> 7) & 7) << 4);
      int row = lg >> 7, kb = lg & 127;
      gload16((const char*)(A + (size_t)(m0 + row) * 768 + k0) + kb, (char*)sA + chunk * 1024);
    }
#pragma unroll
    for (int i = 0; i < 2; ++i) {
      int chunk = i * 4 + w;
      int d = chunk * 1024 + l * 16;
      int lg = d ^ (((d >> 7) & 7) << 4);
      int row = lg >> 7, kb = lg & 127;
      gload16((const char*)(B + (size_t)(n0 + row) * 768 + k0) + kb, (char*)sB + chunk * 1024);
    }
    __syncthreads();
#pragma unroll
    for (int kk = 0; kk < 2; ++kk) {
      bf16x8 av[4], bv[2];
#pragma unroll
      for (int fm = 0; fm < 4; ++fm) {
        int row = wr * 64 + fm * 16 + (l & 15);
        int addr = (row * 128 + kk * 64 + (l >> 4) * 16) ^ ((row & 7) << 4);
        av[fm] = *(const bf16x8*)((const char*)sA + addr);
      }
#pragma unroll
      for (int fn = 0; fn < 2; ++fn) {
        int row = wc * 32 + fn * 16 + (l & 15);
        int addr = (row * 128 + kk * 64 + (l >> 4) * 16) ^ ((row & 7) << 4);
        bv[fn] = *(const bf16x8*)((const char*)sB + addr);
      }
#pragma unroll
      for (int fm = 0; fm < 4; ++fm)
#pragma unroll
        for (int fn = 0; fn < 2; ++fn)
          acc[fm][fn] = __builtin_amdgcn_mfma_f32_16x16x32_bf16(av[fm], bv[fn], acc[fm][fn], 0, 0, 0);
    }
  }
#pragma unroll
  for (int fn = 0; fn < 2; ++fn) {
    int c = n0 + wc * 32 + fn * 16 + (l & 15);
    float bb = bias[c];
#pragma unroll
    for (int fm = 0; fm < 4; ++fm) {
#pragma unroll
      for (int j = 0; j < 4; ++j) {
        int gr = m0 + wr * 64 + fm * 16 + (l >> 4) * 4 + j;
        int tt = gr >> 10, b = gr & 1023;
        dout[(size_t)b * (TLEN * 256) + (size_t)(tt + 1) * 256 + c] = acc[fm][fn][j] + bb;
      }
    }
  }
}

// ---------------- encoder v3: 256 blocks = 128 rowgrps x 2 dirs, 8 rows ----------
struct EncArgs {
  u16* enc_b; u16* hcatB; const int* src;
  const u16* Whhf; const u16* Whhb;
  const float* bhhf; const float* bhhb;
  const float* tabf; const float* tabb;
};

__global__ __launch_bounds__(1024, 4) void k_enc_p(EncArgs E) {
  __shared__ float hF[8 * HFLD];
  __shared__ u16 hB[16 * HLD];  // rows 8-15 stay zero (A-frag over-read)
  __shared__ int toks[256];
  int dir = blockIdx.x & 1;
  int r0 = (blockIdx.x >> 1) * 8;
  int tid = threadIdx.x, w = tid >> 6, l = tid & 63;
  const u16* Whh = dir ? E.Whhb : E.Whhf;
  const float* tab = dir ? E.tabb : E.tabf;
  const float* bhh = dir ? E.bhhb : E.bhhf;
  bf16x8 wreg[8][3];
#pragma unroll
  for (int kk = 0; kk < 8; ++kk)
#pragma unroll
    for (int g = 0; g < 3; ++g)
      wreg[kk][g] = *(const bf16x8*)(Whh +
          (size_t)(g * 256 + w * 16 + (l & 15)) * 256 + kk * 32 + (l >> 4) * 8);
  for (int i = tid; i < 16 * HLD; i += 1024) hB[i] = 0;
  for (int i = tid; i < 8 * HFLD; i += 1024) hF[i] = 0.f;
  if (tid < 256) toks[tid] = E.src[(size_t)(r0 + (tid >> 5)) * SLEN + (tid & 31)];
  __syncthreads();
  for (int s = 0; s < SLEN; ++s) {
    int s_store = dir ? (SLEN - 1 - s) : s;
    f32x4 ae[3] = {};
    if (s > 0) {
#pragma unroll
      for (int kk = 0; kk < 8; ++kk) {
        bf16x8 av = *(const bf16x8*)(hB + (l & 15) * HLD + kk * 32 + (l >> 4) * 8);
#pragma unroll
        for (int g = 0; g < 3; ++g)
          ae[g] = __builtin_amdgcn_mfma_f32_16x16x32_bf16(av, wreg[kk][g], ae[g], 0, 0, 0);
      }
    }
    __syncthreads();
    int c = w * 16 + (l & 15);
    float bR = bhh[c], bZ = bhh[256 + c], bN = bhh[512 + c];
#pragma unroll
    for (int j = 0; j < 4; ++j) {
      int row = (l >> 4) * 4 + j;
      if (row < 8) {
        const float* tb = tab + (size_t)toks[row * 32 + s_store] * 768 + c;
        float rg = sgm(tb[0] + ae[0][j] + bR);
        float zg = sgm(tb[256] + ae[1][j] + bZ);
        float ng = tanh_fast(tb[512] + rg * (ae[2][j] + bN));
        float hold = hF[row * HFLD + c];
        float hv = (1.f - zg) * ng + zg * hold;
        hF[row * HFLD + c] = hv;
        u16 hb16 = f2b(hv);
        hB[row * HLD + c] = hb16;
        E.enc_b[((size_t)(r0 + row) * SLEN + s_store) * 512 + dir * 256 + c] = hb16;
      }
    }
    __syncthreads();
  }
  for (int i = tid; i < 8 * 256; i += 1024) {
    int row = i >> 8, c = i & 255;
    E.hcatB[(size_t)(r0 + row) * 512 + dir * 256 + c] = hB[row * HLD + c];
  }
}

// ---------------- K1: attn8 with fused GRU-epilogue prologue ---------------------
__global__ __launch_bounds__(256) void k_attn8_ep(u16* __restrict__ cat,
                                                  const u16* __restrict__ enc_pre_b,
                                                  const u16* __restrict__ enc_b,
                                                  const float* __restrict__ v_attn,
                                                  const u16* __restrict__ Wd_b,
                                                  u16* __restrict__ bcat_t,
                                                  const float* __restrict__ gbuf,
                                                  const float* __restrict__ gi_prev,
                                                  const float* __restrict__ dbhh,
                                                  const float* __restrict__ h_cur,
                                                  float* __restrict__ h_nxt,
                                                  u16* __restrict__ bcat_prev,
                                                  int do_ep) {
  __shared__ __align__(16) char smem[10240];
  float* hwS = (float*)smem;           // 8 x 256
  float* vS = (float*)(smem + 8192);   // 256
  float* awS = (float*)(smem + 9216);  // 8 x 32
  int b0 = blockIdx.x * 8;
  int tid = threadIdx.x, w = tid >> 6, l = tid & 63;
  vS[tid] = v_attn[tid];
  if (do_ep) {
    int row = b0 + (tid >> 5);
    int c0 = (tid & 31) * 8;
    const float* g = gbuf + (size_t)row * 1024;
    const float* gi = gi_prev + (size_t)(row) * 768;
#pragma unroll
    for (int q = 0; q < 8; ++q) {
      int c = c0 + q;
      float rg = sgm(gi[c] + g[c] + dbhh[c]);
      float zg = sgm(gi[256 + c] + g[256 + c] + dbhh[256 + c]);
      float ng = tanh_fast(gi[512 + c] + g[512 + c] + rg * (g[768 + c] + dbhh[512 + c]));
      float hold = h_cur[(size_t)row * 256 + c];
      float hv = (1.f - zg) * ng + zg * hold;
      h_nxt[(size_t)row * 256 + c] = hv;
      u16 hb = f2b(hv);
      cat[(size_t)row * 768 + 512 + c] = hb;
      bcat_prev[(size_t)row * 768 + c] = hb;
    }
  }
  __syncthreads();
  f32x4 acc[4] = {};
  for (int k0 = 0; k0 < 256; k0 += 32) {
    bf16x8 av = *(const bf16x8*)(cat + (size_t)(b0 + (l & 15)) * 768 + 512 + k0 + (l >> 4) * 8);
#pragma unroll
    for (int fn = 0; fn < 4; ++fn) {
      bf16x8 bv = *(const bf16x8*)(Wd_b + (size_t)(w * 64 + fn * 16 + (l & 15)) * 256 +
                                   k0 + (l >> 4) * 8);
      acc[fn] = __builtin_amdgcn_mfma_f32_16x16x32_bf16(av, bv, acc[fn], 0, 0, 0);
    }
  }
#pragma unroll
  for (int fn = 0; fn < 4; ++fn) {
    int c = w * 64 + fn * 16 + (l & 15);
#pragma unroll
    for (int j = 0; j < 4; ++j) {
      int r = (l >> 4) * 4 + j;
      if (r < 8) hwS[r * 256 + c] = acc[fn][j];
    }
  }
  __syncthreads();
  int r = tid >> 5, s = tid & 31;
  const u16* ep = enc_pre_b + ((size_t)(b0 + r) * SLEN + s) * 256;
  float sum = 0.f;
  for (int a0 = 0; a0 < 256; a0 += 8) {
    bf16x8 pk = *(const bf16x8*)(ep + a0);
    float4 h0 = *(const float4*)&hwS[r * 256 + a0];
    float4 h1 = *(const float4*)&hwS[r * 256 + a0 + 4];
    float4 v0 = *(const float4*)&vS[a0];
    float4 v1 = *(const float4*)&vS[a0 + 4];
    sum += v0.x * tanh_fast(b2f((u16)pk[0]) + h0.x) + v0.y * tanh_fast(b2f((u16)pk[1]) + h0.y) +
           v0.z * tanh_fast(b2f((u16)pk[2]) + h0.z) + v0.w * tanh_fast(b2f((u16)pk[3]) + h0.w) +
           v1.x * tanh_fast(b2f((u16)pk[4]) + h1.x) + v1.y * tanh_fast(b2f((u16)pk[5]) + h1.y) +
           v1.z * tanh_fast(b2f((u16)pk[6]) + h1.z) + v1.w * tanh_fast(b2f((u16)pk[7]) + h1.w);
  }
  float m = sum;
#pragma unroll
  for (int o = 16; o >= 1; o >>= 1) m = fmaxf(m, __shfl_xor(m, o, 32));
  float e = __expf(sum - m), ss = e;
#pragma unroll
  for (int o = 16; o >= 1; o >>= 1) ss += __shfl_xor(ss, o, 32);
  awS[r * 32 + s] = e / ss;
  __syncthreads();
  int c = tid * 2;
#pragma unroll
  for (int rr = 0; rr < 8; ++rr) {
    float ax = 0.f, ay = 0.f;
    const u16* eb = enc_b + (size_t)(b0 + rr) * (SLEN * 512) + c;
#pragma unroll 8
    for (int si = 0; si < 32; ++si) {
      float a = awS[rr * 32 + si];
      unsigned pk = *(const unsigned*)(eb + si * 512);
      float x, y; unpk(pk, x, y);
      ax += a * x; ay += a * y;
    }
    unsigned o = (unsigned)f2b(ax) | ((unsigned)f2b(ay) << 16);
    *(unsigned*)(cat + (size_t)(b0 + rr) * 768 + c) = o;
    *(unsigned*)(bcat_t + (size_t)(b0 + rr) * 768 + 256 + c) = o;
  }
}

// ---------------- final GRU epilogue (t=30) --------------------------------------
__global__ __launch_bounds__(256) void k_gru_ep(const float* __restrict__ gbuf,
                                                const float* __restrict__ gi_t,
                                                const float* __restrict__ dbhh,
                                                const float* __restrict__ h_cur,
                                                float* __restrict__ h_nxt,
                                                u16* __restrict__ bcat_t) {
  int row = blockIdx.x, c = threadIdx.x;
  const float* g = gbuf + (size_t)row * 1024;
  const float* gi = gi_t + (size_t)row * 768;
  float rg = sgm(gi[c] + g[c] + dbhh[c]);
  float zg = sgm(gi[256 + c] + g[256 + c] + dbhh[256 + c]);
  float ng = tanh_fast(gi[512 + c] + g[512 + c] + rg * (g[768 + c] + dbhh[512 + c]));
  float hold = h_cur[(size_t)row * 256 + c];
  float hv = (1.f - zg) * ng + zg * hold;
  h_nxt[(size_t)row * 256 + c] = hv;
  bcat_t[(size_t)row * 768 + c] = f2b(hv);
}

// ---------------- h fp32 -> bf16 into cat[512:768] -------------------------------
__global__ __launch_bounds__(256) void k_h2b(const float* __restrict__ h,
                                             u16* __restrict__ cat) {
  int row = blockIdx.x, c = threadIdx.x;
  cat[(size_t)row * 768 + 512 + c] = f2b(h[(size_t)row * 256 + c]);
}

// ---------------- zero t=0 slice -------------------------------------------------
__global__ __launch_bounds__(256) void k_zero0(float* __restrict__ outp) {
  outp[(size_t)blockIdx.x * (TLEN * 256) + threadIdx.x] = 0.f;
}

extern "C" void kernel_launch(void* const* d_in, const int* in_sizes, int n_in,
                              void* d_out, int out_size, void* d_ws, size_t ws_size,
                              hipStream_t stream) {
  (void)in_sizes; (void)n_in; (void)out_size; (void)ws_size;
  const int* src = (const int*)d_in[0];
  const int* trg = (const int*)d_in[1];
  const float* enc_emb = (const float*)d_in[2];
  const float* eWih_f = (const float*)d_in[3];
  const float* eWhh_f = (const float*)d_in[4];
  const float* ebih_f = (const float*)d_in[5];
  const float* ebhh_f = (const float*)d_in[6];
  const float* eWih_b = (const float*)d_in[7];
  const float* eWhh_b = (const float*)d_in[8];
  const float* ebih_b = (const float*)d_in[9];
  const float* ebhh_b = (const float*)d_in[10];
  const float* Wproj = (const float*)d_in[11];
  const float* bproj = (const float*)d_in[12];
  const float* dec_emb = (const float*)d_in[13];
  const float* Wattn = (const float*)d_in[14];
  const float* battn = (const float*)d_in[15];
  const float* v_attn = (const float*)d_in[16];
  const float* dWih = (const float*)d_in[17];
  const float* dWhh = (const float*)d_in[18];
  const float* dbih = (const float*)d_in[19];
  const float* dbhh = (const float*)d_in[20];
  const float* Wfc = (const float*)d_in[21];
  const float* bfc = (const float*)d_in[22];
  float* dout = (float*)d_out;

  char* base = (char*)d_ws;
  size_t off = 0;
  auto alloc = [&](size_t bytes) {
    void* p = base + off;
    off += (bytes + 255) & ~(size_t)255;
    return p;
  };
  u16* enc_b     = (u16*)alloc((size_t)BSZ * SLEN * 512 * 2);
  u16* enc_pre_b = (u16*)alloc((size_t)BSZ * SLEN * 256 * 2);
  u16* bcat      = (u16*)alloc((size_t)31 * BSZ * 768 * 2);
  float* gi_t    = (float*)alloc((size_t)31 * BSZ * 768 * 4);
  float* gbuf    = (float*)alloc((size_t)BSZ * 1024 * 4);
  float* tabf    = (float*)alloc((size_t)64 * 768 * 4);
  float* tabb    = (float*)alloc((size_t)64 * 768 * 4);
  float* tabd    = (float*)alloc((size_t)256 * 768 * 4);
  u16* hcatB     = (u16*)alloc((size_t)BSZ * 512 * 2);
  float* h0f     = (float*)alloc((size_t)BSZ * 256 * 4);
  float* h1f     = (float*)alloc((size_t)BSZ * 256 * 4);
  u16* Whhf_b    = (u16*)alloc((size_t)768 * 256 * 2);
  u16* Whhb_b    = (u16*)alloc((size_t)768 * 256 * 2);
  u16* We_b      = (u16*)alloc((size_t)256 * 512 * 2);
  u16* Wd_b      = (u16*)alloc((size_t)256 * 256 * 2);
  u16* Wproj_b   = (u16*)alloc((size_t)256 * 512 * 2);
  u16* Wg        = (u16*)alloc((size_t)1024 * 768 * 2);
  u16* Wfc_b     = (u16*)alloc((size_t)256 * 768 * 2);
  u16* cat0      = (u16*)alloc((size_t)BSZ * 768 * 2);
  u16* cat1      = (u16*)alloc((size_t)BSZ * 768 * 2);
  (void)alloc(65536);  // pad: attn8 A-fragments over-read past last rows

  float* hbuf[2] = {h0f, h1f};

  // tables + weight packs
  k_gi_table<<<dim3(64, 3), 256, 0, stream>>>(enc_emb, eWih_f, EDIM, ebih_f, tabf);
  k_gi_table<<<dim3(64, 3), 256, 0, stream>>>(enc_emb, eWih_b, EDIM, ebih_b, tabb);
  k_gi_table<<<dim3(256, 3), 256, 0, stream>>>(dec_emb, dWih, 640, dbih, tabd);
  k_gather<<<dim3(TLEN - 1, BSZ), 256, 0, stream>>>(tabd, trg, gi_t);
  {
    PackArgs P;
    P.dst[0] = Whhf_b;  P.src[0] = eWhh_f; P.ld[0] = 256; P.off[0] = 0;   P.n[0] = 256; P.rows[0] = 768;
    P.dst[1] = Whhb_b;  P.src[1] = eWhh_b; P.ld[1] = 256; P.off[1] = 0;   P.n[1] = 256; P.rows[1] = 768;
    P.dst[2] = We_b;    P.src[2] = Wattn;  P.ld[2] = 768; P.off[2] = 256; P.n[2] = 512; P.rows[2] = 256;
    P.dst[3] = Wd_b;    P.src[3] = Wattn;  P.ld[3] = 768; P.off[3] = 0;   P.n[3] = 256; P.rows[3] = 256;
    P.dst[4] = Wproj_b; P.src[4] = Wproj;  P.ld[4] = 512; P.off[4] = 0;   P.n[4] = 512; P.rows[4] = 256;
    P.dst[5] = Wfc_b;   P.src[5] = Wfc;    P.ld[5] = 768; P.off[5] = 0;   P.n[5] = 768; P.rows[5] = 256;
    k_pack_all<<<dim3(768, 6), 256, 0, stream>>>(P);
  }
  k_pack_gates<<<dim3(1024), 256, 0, stream>>>(Wg, dWih, dWhh);

  // encoder v3: register-resident weights
  {
    EncArgs ea{enc_b, hcatB, src, Whhf_b, Whhb_b, ebhh_f, ebhh_b, tabf, tabb};
    k_enc_p<<<dim3(256), dim3(1024), 0, stream>>>(ea);
  }

  // hdec = hcat @ Wproj^T + bproj (fp32), then bf16 into cat0[512:768]
  k_bgemm<false><<<dim3(8, 4), 256, 0, stream>>>(hcatB, 512, Wproj_b, 512, bproj, h0f, 256, 512);
  k_h2b<<<dim3(BSZ), 256, 0, stream>>>(h0f, cat0);

  // enc_pre (bf16) = enc_b @ We^T + battn
  k_bgemm<true><<<dim3(256, 4), 256, 0, stream>>>(enc_b, 512, We_b, 512, battn,
                                                  enc_pre_b, 256, 512);
  k_zero0<<<dim3(BSZ), 256, 0, stream>>>(dout);

  // decoder: 31 steps x 2 kernels (ep fused into next attn8) + final ep
  for (int t = 0; t < TLEN - 1; ++t) {
    u16* cc = (t & 1) ? cat1 : cat0;
    u16* bt = bcat + (size_t)t * BSZ * 768;
    const float* gip = (t > 0) ? (gi_t + (size_t)(t - 1) * BSZ * 768) : gi_t;
    u16* btp = (t > 0) ? (bcat + (size_t)(t - 1) * BSZ * 768) : bcat;
    k_attn8_ep<<<dim3(128), 256, 0, stream>>>(cc, enc_pre_b, enc_b, v_attn, Wd_b, bt,
                                              gbuf, gip, dbhh, hbuf[(t + 1) & 1],
                                              hbuf[t & 1], btp, (t > 0) ? 1 : 0);
    k_bgemm<false><<<dim3(8, 16), 256, 0, stream>>>(cc, 768, Wg, 768, nullptr, gbuf, 1024, 768);
  }
  // final epilogue for t=30
  k_gru_ep<<<dim3(BSZ), 256, 0, stream>>>(gbuf, gi_t + (size_t)30 * BSZ * 768, dbhh,
                                          hbuf[0], hbuf[1], bcat + (size_t)30 * BSZ * 768);

  // deferred logits
  k_bgemm_logits<<<dim3(248, 4), 256, 0, stream>>>(bcat, Wfc_b, bfc, dout);
}